// Round 11
// baseline (195.730 us; speedup 1.0000x reference)
//
#include <hip/hip_runtime.h>

typedef __attribute__((ext_vector_type(8))) __bf16 bf16x8;
typedef __attribute__((ext_vector_type(4))) float f32x4;
typedef __attribute__((ext_vector_type(4))) int i32x4;

constexpr int Bn = 8192, Nn = 256, M1n = 128, M2n = 64, Mn = 192, ITERS = 30;
constexpr float TAUc = 0.05f, SIGc = 0.05f;

__device__ __forceinline__ ushort f2bf(float f) {
  unsigned u = __builtin_bit_cast(unsigned, f);
  u = (u + 0x7FFFu + ((u >> 16) & 1u)) >> 16;
  return (ushort)u;
}

// packed f32->bf16 (RNE), 2 values per instruction
__device__ __forceinline__ unsigned cvtpk(float lo, float hi) {
  unsigned r;
  asm("v_cvt_pk_bf16_f32 %0, %1, %2" : "=v"(r) : "v"(lo), "v"(hi));
  return r;
}

// Pin a fragment into AGPRs: volatile asm result, cannot be rematerialized.
// MFMA builtins read AGPR operands directly (AV operand class) - no copies.
__device__ __forceinline__ void pina(i32x4& v) { asm volatile("" : "+a"(v)); }

// Builtin MFMA only (r6/r10 lesson: inline-asm MFMA corrupts - allocator may
// overlap asm dst with srcA/B, which builtins' ISel knows to avoid).
__device__ __forceinline__ f32x4 mfma_swp(i32x4 afrag, bf16x8 b, f32x4 acc) {
  return __builtin_amdgcn_mfma_f32_16x16x32_bf16(
      __builtin_bit_cast(bf16x8, afrag), b, acc, 0, 0, 0);
}

// Build bf16 copies of A = [A1;A2] in both orientations:
// Arm[m][n] (192x256 row-major), AT[n][m] (256x192 row-major).
__global__ void prep_kernel(const float* __restrict__ A1, const float* __restrict__ A2,
                            ushort* __restrict__ Arm, ushort* __restrict__ AT) {
  int i = blockIdx.x * 256 + threadIdx.x;
  if (i >= Mn * Nn) return;
  int m = i / Nn, n = i % Nn;
  float v = (m < M1n) ? A1[m * Nn + n] : A2[(m - M1n) * Nn + n];
  ushort b = f2bf(v);
  Arm[m * Nn + n] = b;
  AT[n * Mn + m] = b;
}

// 8 waves per block, ONE 16-row band per block. grid = 512 -> 2 INDEPENDENT
// blocks per CU (decorrelated barriers), 4 waves/SIMD.
// GEMM-1: waves 0-3 -> m-tiles {2w,2w+1} (relu); waves 4-7 -> m-tile {8+(w-4)}
//         (linear). GEMM-3: all waves -> n-tiles {2w,2w+1}.
// Max 28 A-frags pinned in AGPRs (112) - under r8's proven 144 budget.
__global__ __launch_bounds__(512, 4) void pdhg_kernel(
    const float* __restrict__ x0, const float* __restrict__ y10,
    const float* __restrict__ y20, const float* __restrict__ z,
    const float* __restrict__ c, const ushort* __restrict__ Arm,
    const ushort* __restrict__ AT, float* __restrict__ out) {
  __shared__ __align__(16) ushort xb_lds[16][264];  // xbar band (bf16)
  __shared__ __align__(16) ushort y_lds[16][200];   // y band (bf16)

  const int lane = threadIdx.x & 63;
  const int w = threadIdx.x >> 6;     // wave 0..7
  const int fr = lane & 15;           // batch row within band (output col)
  const int kg = lane >> 4;           // k-group / output row-quad
  const int row0 = blockIdx.x * 16;   // this block's 16-row band
  const int rG = row0 + fr;           // this lane's batch row

  const bool isY1 = (w < 4);          // wave-uniform role split
  const int nt0 = 2 * w;              // GEMM-3 n-tiles nt0, nt0+1
  const int mt0 = isY1 ? 2 * w : 8 + (w - 4);
  const int mt1 = 2 * w + 1;          // second m-tile (isY1 only)

  float x[2][4], cv[2][4], ys[2][4], zs[2][4];

  // ---- init x state (dwordx4) + initial xbar into LDS (b64)
#pragma unroll
  for (int t = 0; t < 2; ++t) {
    const int n0 = (nt0 + t) * 16 + kg * 4;
    *reinterpret_cast<f32x4*>(cv[t]) = *reinterpret_cast<const f32x4*>(&c[n0]);
    f32x4 v = *reinterpret_cast<const f32x4*>(&x0[rG * Nn + n0]);
#pragma unroll
    for (int g = 0; g < 4; ++g) x[t][g] = v[g];
    uint2 p = make_uint2(cvtpk(v[0], v[1]), cvtpk(v[2], v[3]));
    *reinterpret_cast<uint2*>(&xb_lds[fr][n0]) = p;
  }
  // ---- init y, sigma*z state (dwordx4)
  {
    const int m0 = mt0 * 16 + kg * 4;
    f32x4 zv = *reinterpret_cast<const f32x4*>(&z[rG * Mn + m0]);
    f32x4 yv = isY1 ? *reinterpret_cast<const f32x4*>(&y10[rG * M1n + m0])
                    : *reinterpret_cast<const f32x4*>(&y20[rG * M2n + (m0 - M1n)]);
#pragma unroll
    for (int g = 0; g < 4; ++g) { zs[0][g] = SIGc * zv[g]; ys[0][g] = yv[g]; }
  }
  if (isY1) {
    const int m0 = mt1 * 16 + kg * 4;
    f32x4 zv = *reinterpret_cast<const f32x4*>(&z[rG * Mn + m0]);
    f32x4 yv = *reinterpret_cast<const f32x4*>(&y10[rG * M1n + m0]);
#pragma unroll
    for (int g = 0; g < 4; ++g) { zs[1][g] = SIGc * zv[g]; ys[1][g] = yv[g]; }
  }

  // ---- preload loop-invariant A fragments into AGPRs (<=28 frags = 112 AGPR)
  i32x4 armF0[8], armF1[8], atF[2][6];
#pragma unroll
  for (int kf = 0; kf < 8; ++kf) {
    armF0[kf] = *reinterpret_cast<const i32x4*>(&Arm[(mt0 * 16 + fr) * Nn + kf * 32 + kg * 8]);
    pina(armF0[kf]);
  }
  if (isY1) {
#pragma unroll
    for (int kf = 0; kf < 8; ++kf) {
      armF1[kf] = *reinterpret_cast<const i32x4*>(&Arm[(mt1 * 16 + fr) * Nn + kf * 32 + kg * 8]);
      pina(armF1[kf]);
    }
  }
#pragma unroll
  for (int t = 0; t < 2; ++t) {
    const int n = (nt0 + t) * 16 + fr;
#pragma unroll
    for (int kf = 0; kf < 6; ++kf) {
      atF[t][kf] = *reinterpret_cast<const i32x4*>(&AT[n * Mn + kf * 32 + kg * 8]);
      pina(atF[t][kf]);
    }
  }

  __syncthreads();

  for (int it = 0; it < ITERS; ++it) {
    // ---- GEMM-1: S = xbar @ A^T; fx streamed (8 reads), 1-2 m-tile chains
    f32x4 a0 = {0.f, 0.f, 0.f, 0.f}, a1 = a0;
    if (isY1) {
#pragma unroll
      for (int kf = 0; kf < 8; ++kf) {
        bf16x8 fx = *reinterpret_cast<const bf16x8*>(&xb_lds[fr][kf * 32 + kg * 8]);
        a0 = mfma_swp(armF0[kf], fx, a0);
        a1 = mfma_swp(armF1[kf], fx, a1);
      }
    } else {
#pragma unroll
      for (int kf = 0; kf < 8; ++kf) {
        bf16x8 fx = *reinterpret_cast<const bf16x8*>(&xb_lds[fr][kf * 32 + kg * 8]);
        a0 = mfma_swp(armF0[kf], fx, a0);
      }
    }

    // ---- y update; write bf16 Y (one ds_write_b64 per tile)
    {
      const int m0 = mt0 * 16 + kg * 4;
#pragma unroll
      for (int g = 0; g < 4; ++g) {
        float s = __builtin_fmaf(SIGc, a0[g], ys[0][g]) - zs[0][g];
        ys[0][g] = isY1 ? fmaxf(s, 0.f) : s;
      }
      uint2 p = make_uint2(cvtpk(ys[0][0], ys[0][1]), cvtpk(ys[0][2], ys[0][3]));
      *reinterpret_cast<uint2*>(&y_lds[fr][m0]) = p;
    }
    if (isY1) {
      const int m0 = mt1 * 16 + kg * 4;
#pragma unroll
      for (int g = 0; g < 4; ++g) {
        float s = __builtin_fmaf(SIGc, a1[g], ys[1][g]) - zs[1][g];
        ys[1][g] = fmaxf(s, 0.f);
      }
      uint2 p = make_uint2(cvtpk(ys[1][0], ys[1][1]), cvtpk(ys[1][2], ys[1][3]));
      *reinterpret_cast<uint2*>(&y_lds[fr][m0]) = p;
    }
    __syncthreads();

    // ---- GEMM-3: G = y @ A; fy streamed (6 reads), 2 n-tile chains
    f32x4 q0 = {0.f, 0.f, 0.f, 0.f}, q1 = q0;
#pragma unroll
    for (int kf = 0; kf < 6; ++kf) {
      bf16x8 fy = *reinterpret_cast<const bf16x8*>(&y_lds[fr][kf * 32 + kg * 8]);
      q0 = mfma_swp(atF[0][kf], fy, q0);
      q1 = mfma_swp(atF[1][kf], fy, q1);
    }

    // ---- x update; write bf16 xbar (one ds_write_b64 per n-tile)
    const bool notlast = (it != ITERS - 1);
#pragma unroll
    for (int t = 0; t < 2; ++t) {
      const int n0 = (nt0 + t) * 16 + kg * 4;
      const f32x4 qt = t ? q1 : q0;
      float xb[4];
#pragma unroll
      for (int g = 0; g < 4; ++g) {
        float grad = cv[t][g] + qt[g];
        float xn = fmaxf(__builtin_fmaf(-TAUc, grad, x[t][g]), 0.f);
        xb[g] = 2.f * xn - x[t][g];  // theta = 1
        x[t][g] = xn;
      }
      if (notlast) {
        uint2 p = make_uint2(cvtpk(xb[0], xb[1]), cvtpk(xb[2], xb[3]));
        *reinterpret_cast<uint2*>(&xb_lds[fr][n0]) = p;
      }
    }
    if (notlast) __syncthreads();
  }

  // ---- store outputs (all dwordx4): x (Bx256), y1 (Bx128), y2 (Bx64)
  float* ox = out;
  float* oy1 = out + Bn * Nn;
  float* oy2 = oy1 + Bn * M1n;
#pragma unroll
  for (int t = 0; t < 2; ++t) {
    const int n0 = (nt0 + t) * 16 + kg * 4;
    f32x4 v;
#pragma unroll
    for (int g = 0; g < 4; ++g) v[g] = x[t][g];
    *reinterpret_cast<f32x4*>(&ox[rG * Nn + n0]) = v;
  }
  {
    const int m0 = mt0 * 16 + kg * 4;
    f32x4 v;
#pragma unroll
    for (int g = 0; g < 4; ++g) v[g] = ys[0][g];
    if (isY1) *reinterpret_cast<f32x4*>(&oy1[rG * M1n + m0]) = v;
    else      *reinterpret_cast<f32x4*>(&oy2[rG * M2n + (m0 - M1n)]) = v;
  }
  if (isY1) {
    const int m0 = mt1 * 16 + kg * 4;
    f32x4 v;
#pragma unroll
    for (int g = 0; g < 4; ++g) v[g] = ys[1][g];
    *reinterpret_cast<f32x4*>(&oy1[rG * M1n + m0]) = v;
  }
}

extern "C" void kernel_launch(void* const* d_in, const int* in_sizes, int n_in,
                              void* d_out, int out_size, void* d_ws, size_t ws_size,
                              hipStream_t stream) {
  const float* x0  = (const float*)d_in[0];
  const float* y10 = (const float*)d_in[1];
  const float* y20 = (const float*)d_in[2];
  const float* z   = (const float*)d_in[3];
  const float* c   = (const float*)d_in[4];
  const float* A1  = (const float*)d_in[5];
  const float* A2  = (const float*)d_in[6];

  ushort* Arm = (ushort*)d_ws;          // 192*256 bf16
  ushort* AT  = Arm + Mn * Nn;          // 256*192 bf16

  prep_kernel<<<(Mn * Nn + 255) / 256, 256, 0, stream>>>(A1, A2, Arm, AT);
  pdhg_kernel<<<Bn / 16, 512, 0, stream>>>(x0, y10, y20, z, c, Arm, AT, (float*)d_out);
}

// Round 12
// 72.866 us; speedup vs baseline: 2.6861x; 2.6861x over previous
//
#include <hip/hip_runtime.h>

typedef __attribute__((ext_vector_type(8))) __bf16 bf16x8;
typedef __attribute__((ext_vector_type(4))) float f32x4;
typedef __attribute__((ext_vector_type(4))) int i32x4;

constexpr int Bn = 8192, Nn = 256, M1n = 128, M2n = 64, Mn = 192, ITERS = 30;
constexpr float TAUc = 0.05f, SIGc = 0.05f;

__device__ __forceinline__ ushort f2bf(float f) {
  unsigned u = __builtin_bit_cast(unsigned, f);
  u = (u + 0x7FFFu + ((u >> 16) & 1u)) >> 16;
  return (ushort)u;
}

__device__ __forceinline__ unsigned cvtpk(float lo, float hi) {
  unsigned r;
  asm("v_cvt_pk_bf16_f32 %0, %1, %2" : "=v"(r) : "v"(lo), "v"(hi));
  return r;
}

// Pin a fragment into AGPRs: volatile asm result, cannot be rematerialized.
__device__ __forceinline__ void pina(i32x4& v) { asm volatile("" : "+a"(v)); }

// Builtin MFMA only (r6/r10: inline-asm MFMA corrupts). Swapped operands:
// A-op = pinned A-matrix fragment, B-op = LDS-streamed x/y fragment.
// Lane(fr,kg) reg g = D[m/n = tile*16+kg*4+g][batch=fr].
__device__ __forceinline__ f32x4 mfma_swp(i32x4 afrag, bf16x8 b, f32x4 acc) {
  return __builtin_amdgcn_mfma_f32_16x16x32_bf16(
      __builtin_bit_cast(bf16x8, afrag), b, acc, 0, 0, 0);
}

__global__ void prep_kernel(const float* __restrict__ A1, const float* __restrict__ A2,
                            ushort* __restrict__ Arm, ushort* __restrict__ AT) {
  int i = blockIdx.x * 256 + threadIdx.x;
  if (i >= Mn * Nn) return;
  int m = i / Nn, n = i % Nn;
  float v = (m < M1n) ? A1[m * Nn + n] : A2[(m - M1n) * Nn + n];
  ushort b = f2bf(v);
  Arm[m * Nn + n] = b;
  AT[n * Mn + m] = b;
}

// 8 waves, 32 rows = bands P(0),Q(1). grid=256 = 1 block/CU, 2 waves/SIMD.
// ANTI-PHASE pipeline: phase A = G1(P) + G3(Q); phase B = G1(Q) + G3(P).
// Two independent chains per phase hide each other's LDS/MFMA latency.
// Wave w: G1 m-tiles {2w,2w+1} (w<4, relu) or {4+w} (w>=4, linear), both bands;
//         G3 n-tiles {2w,2w+1}, one band per phase.
// Max 28 A-frags pinned in AGPRs (112) + ~100 VGPR <= 256 (occ-2 budget).
__global__ __launch_bounds__(512, 2) void pdhg_kernel(
    const float* __restrict__ x0, const float* __restrict__ y10,
    const float* __restrict__ y20, const float* __restrict__ z,
    const float* __restrict__ c, const ushort* __restrict__ Arm,
    const ushort* __restrict__ AT, float* __restrict__ out) {
  __shared__ __align__(16) ushort xb_lds[2][16][264];  // xbar bands (bf16)
  __shared__ __align__(16) ushort y_lds[2][16][200];   // y bands (bf16)

  const int lane = threadIdx.x & 63;
  const int w = threadIdx.x >> 6;     // wave 0..7
  const int fr = lane & 15;           // batch row within band
  const int kg = lane >> 4;           // k-group / output row-quad
  const int row0 = blockIdx.x * 32;   // 32-row super-band

  const bool heavy = (w < 4);         // wave-uniform: 2 m-tiles (relu) vs 1 (linear)
  const int mt0 = heavy ? 2 * w : 4 + w;   // tiles 0..7 relu / 8..11 linear
  const int mt1 = 2 * w + 1;               // heavy only
  const int m00 = mt0 * 16 + kg * 4;
  const int m01 = mt1 * 16 + kg * 4;

  float x[2][2][4];       // [band][n-tile t][g]
  float cv[2][4];
  float ys[2][2][4];      // [band][slot][g]
  float zs[2][2][4];

  // ---- init x state + initial xbar = x0 into LDS (both bands)
#pragma unroll
  for (int t = 0; t < 2; ++t) {
    const int n0 = (2 * w + t) * 16 + kg * 4;
    *reinterpret_cast<f32x4*>(cv[t]) = *reinterpret_cast<const f32x4*>(&c[n0]);
#pragma unroll
    for (int b = 0; b < 2; ++b) {
      f32x4 v = *reinterpret_cast<const f32x4*>(&x0[(row0 + 16 * b + fr) * Nn + n0]);
#pragma unroll
      for (int g = 0; g < 4; ++g) x[b][t][g] = v[g];
      uint2 p = make_uint2(cvtpk(v[0], v[1]), cvtpk(v[2], v[3]));
      *reinterpret_cast<uint2*>(&xb_lds[b][fr][n0]) = p;
    }
  }
  // ---- init y, sigma*z state (both bands)
#pragma unroll
  for (int b = 0; b < 2; ++b) {
    const int rGb = row0 + 16 * b + fr;
    {
      f32x4 zv = *reinterpret_cast<const f32x4*>(&z[rGb * Mn + m00]);
      f32x4 yv = heavy ? *reinterpret_cast<const f32x4*>(&y10[rGb * M1n + m00])
                       : *reinterpret_cast<const f32x4*>(&y20[rGb * M2n + (m00 - M1n)]);
#pragma unroll
      for (int g = 0; g < 4; ++g) { zs[b][0][g] = SIGc * zv[g]; ys[b][0][g] = yv[g]; }
    }
    if (heavy) {
      f32x4 zv = *reinterpret_cast<const f32x4*>(&z[rGb * Mn + m01]);
      f32x4 yv = *reinterpret_cast<const f32x4*>(&y10[rGb * M1n + m01]);
#pragma unroll
      for (int g = 0; g < 4; ++g) { zs[b][1][g] = SIGc * zv[g]; ys[b][1][g] = yv[g]; }
    }
  }

  // ---- preload loop-invariant A fragments into AGPRs (<=28 frags = 112 AGPR)
  i32x4 armF[2][8], atF[2][6];
#pragma unroll
  for (int kf = 0; kf < 8; ++kf) {
    armF[0][kf] = *reinterpret_cast<const i32x4*>(&Arm[(mt0 * 16 + fr) * Nn + kf * 32 + kg * 8]);
    pina(armF[0][kf]);
  }
  if (heavy) {
#pragma unroll
    for (int kf = 0; kf < 8; ++kf) {
      armF[1][kf] = *reinterpret_cast<const i32x4*>(&Arm[(mt1 * 16 + fr) * Nn + kf * 32 + kg * 8]);
      pina(armF[1][kf]);
    }
  }
#pragma unroll
  for (int t = 0; t < 2; ++t) {
    const int n = (2 * w + t) * 16 + fr;
#pragma unroll
    for (int kf = 0; kf < 6; ++kf) {
      atF[t][kf] = *reinterpret_cast<const i32x4*>(&AT[n * Mn + kf * 32 + kg * 8]);
      pina(atF[t][kf]);
    }
  }

  // G1 on band b: y[b] <- update(y[b], xbar[b]); writes y_lds[b].
  auto do_g1 = [&](int b) {
    f32x4 h0 = {0.f, 0.f, 0.f, 0.f}, h1 = h0;
    if (heavy) {
#pragma unroll
      for (int kf = 0; kf < 8; ++kf) {
        bf16x8 fx = *reinterpret_cast<const bf16x8*>(&xb_lds[b][fr][kf * 32 + kg * 8]);
        h0 = mfma_swp(armF[0][kf], fx, h0);
        h1 = mfma_swp(armF[1][kf], fx, h1);
      }
    } else {
#pragma unroll
      for (int kf = 0; kf < 8; ++kf) {
        bf16x8 fx = *reinterpret_cast<const bf16x8*>(&xb_lds[b][fr][kf * 32 + kg * 8]);
        h0 = mfma_swp(armF[0][kf], fx, h0);
      }
    }
#pragma unroll
    for (int g = 0; g < 4; ++g) {
      float s = __builtin_fmaf(SIGc, h0[g], ys[b][0][g]) - zs[b][0][g];
      ys[b][0][g] = heavy ? fmaxf(s, 0.f) : s;
    }
    {
      uint2 p = make_uint2(cvtpk(ys[b][0][0], ys[b][0][1]), cvtpk(ys[b][0][2], ys[b][0][3]));
      *reinterpret_cast<uint2*>(&y_lds[b][fr][m00]) = p;
    }
    if (heavy) {
#pragma unroll
      for (int g = 0; g < 4; ++g) {
        float s = __builtin_fmaf(SIGc, h1[g], ys[b][1][g]) - zs[b][1][g];
        ys[b][1][g] = fmaxf(s, 0.f);
      }
      uint2 p = make_uint2(cvtpk(ys[b][1][0], ys[b][1][1]), cvtpk(ys[b][1][2], ys[b][1][3]));
      *reinterpret_cast<uint2*>(&y_lds[b][fr][m01]) = p;
    }
  };

  // G3 on band b: x[b] <- update(x[b], y[b]); writes xbar to xb_lds[b].
  auto do_g3 = [&](int b) {
    f32x4 q0 = {0.f, 0.f, 0.f, 0.f}, q1 = q0;
#pragma unroll
    for (int kf = 0; kf < 6; ++kf) {
      bf16x8 fy = *reinterpret_cast<const bf16x8*>(&y_lds[b][fr][kf * 32 + kg * 8]);
      q0 = mfma_swp(atF[0][kf], fy, q0);
      q1 = mfma_swp(atF[1][kf], fy, q1);
    }
#pragma unroll
    for (int t = 0; t < 2; ++t) {
      const int n0 = (2 * w + t) * 16 + kg * 4;
      const f32x4 qt = t ? q1 : q0;
      float xb[4];
#pragma unroll
      for (int g = 0; g < 4; ++g) {
        float grad = cv[t][g] + qt[g];
        float xn = fmaxf(__builtin_fmaf(-TAUc, grad, x[b][t][g]), 0.f);
        xb[g] = 2.f * xn - x[b][t][g];  // theta = 1
        x[b][t][g] = xn;
      }
      uint2 p = make_uint2(cvtpk(xb[0], xb[1]), cvtpk(xb[2], xb[3]));
      *reinterpret_cast<uint2*>(&xb_lds[b][fr][n0]) = p;
    }
  };

  __syncthreads();

  // ---- prologue: yQ(1) from xbarQ(0)=x0
  do_g1(1);
  __syncthreads();

  // ---- anti-phase main loop: band Q runs half an iteration ahead on y
  for (int it = 1; it <= ITERS; ++it) {
    // Phase A: G1(P) -> yP(it)  ||  G3(Q) -> xQ(it), xbarQ(it)
    do_g1(0);
    do_g3(1);
    __syncthreads();
    // Phase B: G1(Q) -> yQ(it+1)  ||  G3(P) -> xP(it), xbarP(it)
    if (it < ITERS) do_g1(1);
    do_g3(0);
    if (it < ITERS) __syncthreads();
  }

  // ---- store outputs (dwordx4): x (Bx256), y1 (Bx128), y2 (Bx64)
  float* ox = out;
  float* oy1 = out + Bn * Nn;
  float* oy2 = oy1 + Bn * M1n;
#pragma unroll
  for (int b = 0; b < 2; ++b) {
    const int rGb = row0 + 16 * b + fr;
#pragma unroll
    for (int t = 0; t < 2; ++t) {
      const int n0 = (2 * w + t) * 16 + kg * 4;
      f32x4 v;
#pragma unroll
      for (int g = 0; g < 4; ++g) v[g] = x[b][t][g];
      *reinterpret_cast<f32x4*>(&ox[rGb * Nn + n0]) = v;
    }
    {
      f32x4 v;
#pragma unroll
      for (int g = 0; g < 4; ++g) v[g] = ys[b][0][g];
      if (heavy) *reinterpret_cast<f32x4*>(&oy1[rGb * M1n + m00]) = v;
      else       *reinterpret_cast<f32x4*>(&oy2[rGb * M2n + (m00 - M1n)]) = v;
    }
    if (heavy) {
      f32x4 v;
#pragma unroll
      for (int g = 0; g < 4; ++g) v[g] = ys[b][1][g];
      *reinterpret_cast<f32x4*>(&oy1[rGb * M1n + m01]) = v;
    }
  }
}

extern "C" void kernel_launch(void* const* d_in, const int* in_sizes, int n_in,
                              void* d_out, int out_size, void* d_ws, size_t ws_size,
                              hipStream_t stream) {
  const float* x0  = (const float*)d_in[0];
  const float* y10 = (const float*)d_in[1];
  const float* y20 = (const float*)d_in[2];
  const float* z   = (const float*)d_in[3];
  const float* c   = (const float*)d_in[4];
  const float* A1  = (const float*)d_in[5];
  const float* A2  = (const float*)d_in[6];

  ushort* Arm = (ushort*)d_ws;          // 192*256 bf16
  ushort* AT  = Arm + Mn * Nn;          // 256*192 bf16

  prep_kernel<<<(Mn * Nn + 255) / 256, 256, 0, stream>>>(A1, A2, Arm, AT);
  pdhg_kernel<<<Bn / 32, 512, 0, stream>>>(x0, y10, y20, z, c, Arm, AT, (float*)d_out);
}

// Round 13
// 68.265 us; speedup vs baseline: 2.8672x; 1.0674x over previous
//
#include <hip/hip_runtime.h>

typedef __attribute__((ext_vector_type(8))) __bf16 bf16x8;
typedef __attribute__((ext_vector_type(4))) float f32x4;
typedef __attribute__((ext_vector_type(4))) int i32x4;

constexpr int Bn = 8192, Nn = 256, M1n = 128, M2n = 64, Mn = 192, ITERS = 30;
constexpr float TAUc = 0.05f, SIGc = 0.05f;

__device__ __forceinline__ ushort f2bf(float f) {
  unsigned u = __builtin_bit_cast(unsigned, f);
  u = (u + 0x7FFFu + ((u >> 16) & 1u)) >> 16;
  return (ushort)u;
}

// packed f32->bf16 (RNE), 2 values per instruction
__device__ __forceinline__ unsigned cvtpk(float lo, float hi) {
  unsigned r;
  asm("v_cvt_pk_bf16_f32 %0, %1, %2" : "=v"(r) : "v"(lo), "v"(hi));
  return r;
}

// Pin a fragment into AGPRs: volatile asm result, cannot be rematerialized.
__device__ __forceinline__ void pina(i32x4& v) { asm volatile("" : "+a"(v)); }

// SWAPPED builtin MFMA: A-operand = pinned A-matrix fragment, B-operand = the
// LDS-streamed x/y fragment. Lane(fr,kg) reg g = D[m/n = tile*16+kg*4+g][batch=fr].
__device__ __forceinline__ f32x4 mfma_swp(i32x4 afrag, bf16x8 b, f32x4 acc) {
  return __builtin_amdgcn_mfma_f32_16x16x32_bf16(
      __builtin_bit_cast(bf16x8, afrag), b, acc, 0, 0, 0);
}

// Build bf16 copies of A = [A1;A2] in both orientations:
// Arm[m][n] (192x256 row-major), AT[n][m] (256x192 row-major).
__global__ void prep_kernel(const float* __restrict__ A1, const float* __restrict__ A2,
                            ushort* __restrict__ Arm, ushort* __restrict__ AT) {
  int i = blockIdx.x * 256 + threadIdx.x;
  if (i >= Mn * Nn) return;
  int m = i / Nn, n = i % Nn;
  float v = (m < M1n) ? A1[m * Nn + n] : A2[(m - M1n) * Nn + n];
  ushort b = f2bf(v);
  Arm[m * Nn + n] = b;
  AT[n * Mn + m] = b;
}

// 8 waves, 32 rows (2 bands). grid = 256 = 1 block/CU, 2 waves/SIMD.
// GEMM-1 (band-split): wave w -> band w&1, m-tiles {3*(w>>1)+0..2} (8 fx reads).
// GEMM-3: n-tiles {2w,2w+1} x both bands (12 fy reads; atF reused across bands).
// 36 A-frags pinned in AGPRs (144) = the proven no-spill budget at occ 2.
// r13 delta vs r8: s_setprio(1) around MFMA clusters (T5 wave arbitration).
__global__ __launch_bounds__(512, 2) void pdhg_kernel(
    const float* __restrict__ x0, const float* __restrict__ y10,
    const float* __restrict__ y20, const float* __restrict__ z,
    const float* __restrict__ c, const ushort* __restrict__ Arm,
    const ushort* __restrict__ AT, float* __restrict__ out) {
  __shared__ __align__(16) ushort xb_lds[2][16][264];  // xbar bands (bf16)
  __shared__ __align__(16) ushort y_lds[2][16][200];   // y bands (bf16)

  const int lane = threadIdx.x & 63;
  const int w = threadIdx.x >> 6;     // wave 0..7
  const int fr = lane & 15;           // batch row within band (output col)
  const int kg = lane >> 4;           // k-group / output row-quad
  const int row0 = blockIdx.x * 32;   // 32-row super-band

  const int b1 = w & 1;               // GEMM-1 band
  const int mg = w >> 1;              // GEMM-1 m-tile group: tiles 3mg..3mg+2
  const int rG1 = row0 + 16 * b1 + fr;  // GEMM-1 batch row of this lane

  float x[2][2][4];     // [n-tile t][band b][g]
  float cv[2][4];
  float ys[3][4], zs[3][4];

  // ---- init x state (dwordx4) + initial xbar into LDS (b64)
#pragma unroll
  for (int t = 0; t < 2; ++t) {
    const int n0 = (2 * w + t) * 16 + kg * 4;
    *reinterpret_cast<f32x4*>(cv[t]) = *reinterpret_cast<const f32x4*>(&c[n0]);
#pragma unroll
    for (int b = 0; b < 2; ++b) {
      f32x4 v = *reinterpret_cast<const f32x4*>(&x0[(row0 + 16 * b + fr) * Nn + n0]);
#pragma unroll
      for (int g = 0; g < 4; ++g) x[t][b][g] = v[g];
      uint2 p = make_uint2(cvtpk(v[0], v[1]), cvtpk(v[2], v[3]));
      *reinterpret_cast<uint2*>(&xb_lds[b][fr][n0]) = p;
    }
  }
  // ---- init y, sigma*z state (dwordx4; band b1 only)
#pragma unroll
  for (int i = 0; i < 3; ++i) {
    const int mt = 3 * mg + i;
    const int m0 = mt * 16 + kg * 4;
    f32x4 zv = *reinterpret_cast<const f32x4*>(&z[rG1 * Mn + m0]);
    f32x4 yv = (mt < 8) ? *reinterpret_cast<const f32x4*>(&y10[rG1 * M1n + m0])
                        : *reinterpret_cast<const f32x4*>(&y20[rG1 * M2n + (m0 - M1n)]);
#pragma unroll
    for (int g = 0; g < 4; ++g) { zs[i][g] = SIGc * zv[g]; ys[i][g] = yv[g]; }
  }

  // ---- preload loop-invariant A fragments into AGPRs (36 frags = 144 AGPR)
  i32x4 armF[3][8], atF[2][6];
#pragma unroll
  for (int i = 0; i < 3; ++i) {
    const int m = (3 * mg + i) * 16 + fr;
#pragma unroll
    for (int kf = 0; kf < 8; ++kf) {
      armF[i][kf] = *reinterpret_cast<const i32x4*>(&Arm[m * Nn + kf * 32 + kg * 8]);
      pina(armF[i][kf]);
    }
  }
#pragma unroll
  for (int t = 0; t < 2; ++t) {
    const int n = (2 * w + t) * 16 + fr;
#pragma unroll
    for (int kf = 0; kf < 6; ++kf) {
      atF[t][kf] = *reinterpret_cast<const i32x4*>(&AT[n * Mn + kf * 32 + kg * 8]);
      pina(atF[t][kf]);
    }
  }

  __syncthreads();

  for (int it = 0; it < ITERS; ++it) {
    // ---- GEMM-1: band b1 only; fx streamed (8 reads), 3 m-tile chains
    f32x4 a0 = {0.f, 0.f, 0.f, 0.f}, a1 = a0, a2 = a0;
    __builtin_amdgcn_s_setprio(1);
#pragma unroll
    for (int kf = 0; kf < 8; ++kf) {
      bf16x8 fx = *reinterpret_cast<const bf16x8*>(&xb_lds[b1][fr][kf * 32 + kg * 8]);
      a0 = mfma_swp(armF[0][kf], fx, a0);
      a1 = mfma_swp(armF[1][kf], fx, a1);
      a2 = mfma_swp(armF[2][kf], fx, a2);
    }
    __builtin_amdgcn_s_setprio(0);

    // ---- y update; write bf16 Y (one ds_write_b64 per tile)
#pragma unroll
    for (int i = 0; i < 3; ++i) {
      const int mt = 3 * mg + i;
      const int m0 = mt * 16 + kg * 4;
      const f32x4 ai = (i == 0) ? a0 : (i == 1) ? a1 : a2;
      const bool relu = (mt < 8);
#pragma unroll
      for (int g = 0; g < 4; ++g) {
        float s = __builtin_fmaf(SIGc, ai[g], ys[i][g]) - zs[i][g];
        ys[i][g] = relu ? fmaxf(s, 0.f) : s;
      }
      uint2 p = make_uint2(cvtpk(ys[i][0], ys[i][1]), cvtpk(ys[i][2], ys[i][3]));
      *reinterpret_cast<uint2*>(&y_lds[b1][fr][m0]) = p;
    }
    __syncthreads();

    // ---- GEMM-3: both bands, 2 n-tiles; fy streamed (12 reads), 4 chains
    f32x4 q00 = {0.f, 0.f, 0.f, 0.f}, q01 = q00, q10 = q00, q11 = q00;  // q{band}{t}
    __builtin_amdgcn_s_setprio(1);
#pragma unroll
    for (int kf = 0; kf < 6; ++kf) {
      bf16x8 g0 = *reinterpret_cast<const bf16x8*>(&y_lds[0][fr][kf * 32 + kg * 8]);
      bf16x8 g1 = *reinterpret_cast<const bf16x8*>(&y_lds[1][fr][kf * 32 + kg * 8]);
      q00 = mfma_swp(atF[0][kf], g0, q00);
      q01 = mfma_swp(atF[1][kf], g0, q01);
      q10 = mfma_swp(atF[0][kf], g1, q10);
      q11 = mfma_swp(atF[1][kf], g1, q11);
    }
    __builtin_amdgcn_s_setprio(0);

    // ---- x update; write bf16 xbar (one ds_write_b64 per tile x band)
    const bool notlast = (it != ITERS - 1);
#pragma unroll
    for (int t = 0; t < 2; ++t) {
      const int n0 = (2 * w + t) * 16 + kg * 4;
#pragma unroll
      for (int b = 0; b < 2; ++b) {
        const f32x4 qt = (t == 0) ? (b == 0 ? q00 : q10) : (b == 0 ? q01 : q11);
        float xb[4];
#pragma unroll
        for (int g = 0; g < 4; ++g) {
          float grad = cv[t][g] + qt[g];
          float xn = fmaxf(__builtin_fmaf(-TAUc, grad, x[t][b][g]), 0.f);
          xb[g] = 2.f * xn - x[t][b][g];  // theta = 1
          x[t][b][g] = xn;
        }
        if (notlast) {
          uint2 p = make_uint2(cvtpk(xb[0], xb[1]), cvtpk(xb[2], xb[3]));
          *reinterpret_cast<uint2*>(&xb_lds[b][fr][n0]) = p;
        }
      }
    }
    if (notlast) __syncthreads();
  }

  // ---- store outputs (all dwordx4): x (Bx256), y1 (Bx128), y2 (Bx64)
  float* ox = out;
  float* oy1 = out + Bn * Nn;
  float* oy2 = oy1 + Bn * M1n;
#pragma unroll
  for (int t = 0; t < 2; ++t) {
    const int n0 = (2 * w + t) * 16 + kg * 4;
#pragma unroll
    for (int b = 0; b < 2; ++b) {
      f32x4 v;
#pragma unroll
      for (int g = 0; g < 4; ++g) v[g] = x[t][b][g];
      *reinterpret_cast<f32x4*>(&ox[(row0 + 16 * b + fr) * Nn + n0]) = v;
    }
  }
#pragma unroll
  for (int i = 0; i < 3; ++i) {
    const int mt = 3 * mg + i;
    const int m0 = mt * 16 + kg * 4;
    f32x4 v;
#pragma unroll
    for (int g = 0; g < 4; ++g) v[g] = ys[i][g];
    if (mt < 8) *reinterpret_cast<f32x4*>(&oy1[rG1 * M1n + m0]) = v;
    else        *reinterpret_cast<f32x4*>(&oy2[rG1 * M2n + (m0 - M1n)]) = v;
  }
}

extern "C" void kernel_launch(void* const* d_in, const int* in_sizes, int n_in,
                              void* d_out, int out_size, void* d_ws, size_t ws_size,
                              hipStream_t stream) {
  const float* x0  = (const float*)d_in[0];
  const float* y10 = (const float*)d_in[1];
  const float* y20 = (const float*)d_in[2];
  const float* z   = (const float*)d_in[3];
  const float* c   = (const float*)d_in[4];
  const float* A1  = (const float*)d_in[5];
  const float* A2  = (const float*)d_in[6];

  ushort* Arm = (ushort*)d_ws;          // 192*256 bf16
  ushort* AT  = Arm + Mn * Nn;          // 256*192 bf16

  prep_kernel<<<(Mn * Nn + 255) / 256, 256, 0, stream>>>(A1, A2, Arm, AT);
  pdhg_kernel<<<Bn / 32, 512, 0, stream>>>(x0, y10, y20, z, c, Arm, AT, (float*)d_out);
}